// Round 7
// baseline (327.739 us; speedup 1.0000x reference)
//
#include <hip/hip_runtime.h>
#include <math.h>

// Problem constants
static constexpr int B_  = 2;
static constexpr int T_  = 512;
static constexpr int S_  = 2048;
static constexpr int H_  = 768;
static constexpr int L_  = 32;
static constexpr int NH_ = 12;
static constexpr int HD_ = 64;   // H/NH
static constexpr int IM_ = 3072; // 4*H

typedef __bf16 bf16x8 __attribute__((ext_vector_type(8)));
typedef float  f32x4  __attribute__((ext_vector_type(4)));

__device__ __forceinline__ float bf2f(unsigned short u) {
    return __uint_as_float(((unsigned)u) << 16);
}
__device__ __forceinline__ unsigned short f2bf(float f) {
    unsigned u = __float_as_uint(f);
    u += 0x7fffu + ((u >> 16) & 1u);   // RNE
    return (unsigned short)(u >> 16);
}
__device__ __forceinline__ void gl_lds16(const void* g, void* l) {
    __builtin_amdgcn_global_load_lds((const __attribute__((address_space(1))) void*)g,
                                     (__attribute__((address_space(3))) void*)l, 16, 0, 0);
}

// ---------------------------------------------------------------------------
// Mask normalization (int32 vs packed-byte autodetect)
__global__ void k_mask(const int* __restrict__ raw, int* __restrict__ mout) {
    __shared__ int bad;
    if (threadIdx.x == 0) bad = 0;
    __syncthreads();
    int v = raw[threadIdx.x];
    if (v != 0 && v != 1) bad = 1;
    __syncthreads();
    int byte_layout = bad;
    const unsigned char* rb = (const unsigned char*)raw;
    for (int i = threadIdx.x; i < B_ * S_; i += 1024)
        mout[i] = byte_layout ? (int)rb[i] : raw[i];
}

// q[i] = dq . Wq[i,:] + bq[i]  — one wave per output row (coalesced over h)
__global__ void k_q(const float* __restrict__ dq, const float* __restrict__ w,
                    const float* __restrict__ b, float* __restrict__ q) {
    int wv = threadIdx.x >> 6, lane = threadIdx.x & 63;
    int i = blockIdx.x * 4 + wv;
    const float* row = w + (size_t)i * H_;
    float acc = 0.f;
#pragma unroll
    for (int k = 0; k < 12; ++k) acc += dq[lane + 64 * k] * row[lane + 64 * k];
    for (int m = 32; m; m >>= 1) acc += __shfl_xor(acc, m, 64);
    if (lane == 0) q[i] = acc + b[i];
}

// Wq_eff[n,hh] = sum_d q[n*64+d] * Wk[n*64+d, hh]
__global__ void k_wqeff(const float* __restrict__ q, const float* __restrict__ w,
                        float* __restrict__ wq) {
    int i = blockIdx.x * 256 + threadIdx.x;
    if (i >= NH_ * H_) return;
    int n = i / H_, hh = i % H_;
    float acc = 0.f;
    for (int d = 0; d < HD_; ++d)
        acc += q[n * HD_ + d] * w[(size_t)(H_ + n * HD_ + d) * H_ + hh];
    wq[i] = acc;
}

// Fused weight cast: all four weight matrices fp32->bf16, 8 elems/thread.
__global__ void k_castw(const float* __restrict__ s0, const float* __restrict__ s1,
                        const float* __restrict__ s2, const float* __restrict__ s3,
                        unsigned short* __restrict__ d0, unsigned short* __restrict__ d1,
                        unsigned short* __restrict__ d2, unsigned short* __restrict__ d3) {
    const long n0 = (long)H_ * H_, n2 = (long)IM_ * H_;
    long gid = (long)(blockIdx.x * 256 + threadIdx.x) * 8;
    const float* s; unsigned short* d; long off;
    if (gid < n0)                { s = s0; d = d0; off = gid; }
    else if (gid < 2 * n0)       { s = s1; d = d1; off = gid - n0; }
    else if (gid < 2 * n0 + n2)  { s = s2; d = d2; off = gid - 2 * n0; }
    else                         { s = s3; d = d3; off = gid - 2 * n0 - n2; }
    float4 f0 = *(const float4*)(s + off);
    float4 f1 = *(const float4*)(s + off + 4);
    uint4 o;
    o.x = (unsigned)f2bf(f0.x) | ((unsigned)f2bf(f0.y) << 16);
    o.y = (unsigned)f2bf(f0.z) | ((unsigned)f2bf(f0.w) << 16);
    o.z = (unsigned)f2bf(f1.x) | ((unsigned)f2bf(f1.y) << 16);
    o.w = (unsigned)f2bf(f1.z) | ((unsigned)f2bf(f1.w) << 16);
    *(uint4*)(d + off) = o;
}

// generic fp32 -> bf16 cast, 8 elems/thread
__global__ void k_castv(const float* __restrict__ src, unsigned short* __restrict__ dst, int n) {
    int i = (blockIdx.x * 256 + threadIdx.x) * 8;
    if (i >= n) return;
    float4 f0 = *(const float4*)(src + i);
    float4 f1 = *(const float4*)(src + i + 4);
    uint4 o;
    o.x = (unsigned)f2bf(f0.x) | ((unsigned)f2bf(f0.y) << 16);
    o.y = (unsigned)f2bf(f0.z) | ((unsigned)f2bf(f0.w) << 16);
    o.z = (unsigned)f2bf(f1.x) | ((unsigned)f2bf(f1.y) << 16);
    o.w = (unsigned)f2bf(f1.z) | ((unsigned)f2bf(f1.w) << 16);
    *(uint4*)(dst + i) = o;
}

// x_bf = bf16(token_reps + pe), 8 elems/thread
__global__ void k_addpe(const float* __restrict__ tr, const float* __restrict__ pe,
                        unsigned short* __restrict__ x) {
    int i = (blockIdx.x * 256 + threadIdx.x) * 8;
    if (i >= B_ * T_ * H_) return;
    float4 a0 = *(const float4*)(tr + i);
    float4 a1 = *(const float4*)(tr + i + 4);
    const float* pp = pe + (i % (T_ * H_));
    float4 p0 = *(const float4*)pp;
    float4 p1 = *(const float4*)(pp + 4);
    uint4 o;
    o.x = (unsigned)f2bf(a0.x + p0.x) | ((unsigned)f2bf(a0.y + p0.y) << 16);
    o.y = (unsigned)f2bf(a0.z + p0.z) | ((unsigned)f2bf(a0.w + p0.w) << 16);
    o.z = (unsigned)f2bf(a1.x + p1.x) | ((unsigned)f2bf(a1.y + p1.y) << 16);
    o.w = (unsigned)f2bf(a1.z + p1.z) | ((unsigned)f2bf(a1.w + p1.w) << 16);
    *(uint4*)(x + i) = o;
}

// stok[bt,n] = x_bf[bt,:] . wqeff[n,:]
__global__ void k_stok(const unsigned short* __restrict__ x, const float* __restrict__ wq,
                       float* __restrict__ stok) {
    int bt = blockIdx.x;
    int lane = threadIdx.x & 63, w = threadIdx.x >> 6;
    const unsigned short* xr = x + (size_t)bt * H_;
    float xv[12];
#pragma unroll
    for (int k = 0; k < 12; ++k) xv[k] = bf2f(xr[lane + 64 * k]);
#pragma unroll
    for (int hh = 0; hh < 3; ++hh) {
        int n = w * 3 + hh;
        const float* wr = wq + (size_t)n * H_;
        float acc = 0.f;
#pragma unroll
        for (int k = 0; k < 12; ++k) acc += xv[k] * wr[lane + 64 * k];
        for (int m = 32; m; m >>= 1) acc += __shfl_xor(acc, m, 64);
        if (lane == 0) stok[bt * NH_ + n] = acc;
    }
}

// ---------------------------------------------------------------------------
// bf16 MFMA GEMM, m97-style single-buffer + split-K.
// C[M,N] (+)= A[M,kOff:kOff+kLen] @ W[N,kOff:kOff+kLen]^T (+ bias on chunk 0).
// 128x128 tile, BK=64, 256 thr = 4 waves, wave 64x64 = 4x4 MFMA 16x16x32.
// XOR bank swizzle (16B chunk ^= row&7) on staging and fragment reads (R6:
// verified 0 bank conflicts). ATOMIC => fp32 atomicAdd epilogue (split-K).
// 32 KB LDS => up to 5 blocks/CU; grids are 768 => 3 blocks/CU, the m97
// plateau regime where sibling blocks hide the barrier drain (m114).
template <bool RELU, bool OBF, bool ATOMIC>
__global__ __launch_bounds__(256)
void gemm_bt(const unsigned short* __restrict__ A, const unsigned short* __restrict__ W,
             const float* __restrict__ bias, void* __restrict__ Cout,
             int M, int N, int K, int kLen) {
    __shared__ unsigned short As[8192];    // 128 rows x 64 cols bf16
    __shared__ unsigned short Bs[8192];
    const int bm = blockIdx.y * 128, bn = blockIdx.x * 128;
    const int kOff = blockIdx.z * kLen;
    const int tid = threadIdx.x, lane = tid & 63, wid = tid >> 6;   // 0..3
    const int wm = (wid >> 1) * 64, wn = (wid & 1) * 64;
    // staging: wave stages 32 rows of A-tile and 32 rows of B-tile.
    const int r8 = lane >> 3, c8 = lane & 7;
    const int swc = (c8 ^ r8) * 8;                     // swizzled chunk offset
    const unsigned short* agp = A + (size_t)(bm + wid * 32 + r8) * K + kOff + swc;
    const unsigned short* bgp = W + (size_t)(bn + wid * 32 + r8) * K + kOff + swc;
    unsigned short* lA = As + wid * 2048;              // wave-uniform bases
    unsigned short* lB = Bs + wid * 2048;

    f32x4 acc[4][4];
#pragma unroll
    for (int i = 0; i < 4; ++i)
#pragma unroll
        for (int j = 0; j < 4; ++j) acc[i][j] = f32x4{0.f, 0.f, 0.f, 0.f};

    const int mrow = lane & 15;
    const int l7 = lane & 7;
    const int cq0 = lane >> 4;             // 16B chunk within 32-k window
    const int NIT = kLen >> 6;

    for (int it = 0; it < NIT; ++it) {
        const int k0 = it << 6;
#pragma unroll
        for (int j = 0; j < 4; ++j) {
            gl_lds16(agp + (size_t)(8 * j) * K + k0, lA + j * 512);
            gl_lds16(bgp + (size_t)(8 * j) * K + k0, lB + j * 512);
        }
        __syncthreads();                   // drains vmcnt: tile staged
        bf16x8 af[2][4], bfr[2][4];
#pragma unroll
        for (int s = 0; s < 2; ++s) {
            const int cq = s * 4 + cq0;
            const int sw = (cq ^ l7) * 8;
#pragma unroll
            for (int i = 0; i < 4; ++i)
                af[s][i] = *(const bf16x8*)(As + (wm + i * 16 + mrow) * 64 + sw);
#pragma unroll
            for (int j = 0; j < 4; ++j)
                bfr[s][j] = *(const bf16x8*)(Bs + (wn + j * 16 + mrow) * 64 + sw);
        }
#pragma unroll
        for (int s = 0; s < 2; ++s)
#pragma unroll
            for (int i = 0; i < 4; ++i)
#pragma unroll
                for (int j = 0; j < 4; ++j)
                    acc[i][j] = __builtin_amdgcn_mfma_f32_16x16x32_bf16(af[s][i], bfr[s][j], acc[i][j], 0, 0, 0);
        __syncthreads();                   // all waves done reading
    }

    // epilogue: C/D layout col=lane&15, row=(lane>>4)*4+reg (verified m89/m91)
    const bool addb = !ATOMIC || blockIdx.z == 0;
    const int lr = (lane >> 4) * 4, lc = lane & 15;
#pragma unroll
    for (int j = 0; j < 4; ++j) {
        int col = bn + wn + j * 16 + lc;
        float bv = addb ? bias[col] : 0.f;
#pragma unroll
        for (int i = 0; i < 4; ++i) {
            int row0 = bm + wm + i * 16 + lr;
#pragma unroll
            for (int r = 0; r < 4; ++r) {
                float v = acc[i][j][r] + bv;
                if (RELU) v = fmaxf(v, 0.f);
                if (ATOMIC)
                    atomicAdd(&((float*)Cout)[(size_t)(row0 + r) * N + col], v);
                else if (OBF)
                    ((unsigned short*)Cout)[(size_t)(row0 + r) * N + col] = f2bf(v);
                else
                    ((float*)Cout)[(size_t)(row0 + r) * N + col] = v;
            }
        }
    }
}

// ---------------------------------------------------------------------------
// Per-span attention pooling
__global__ void k_attn(const float* __restrict__ stok, const unsigned short* __restrict__ vtok,
                       const int* __restrict__ span_ids, const int* __restrict__ masks,
                       unsigned short* __restrict__ ctx) {
    int r = blockIdx.x, b = r / S_;
    unsigned short* out = ctx + (size_t)r * H_;
    int tid = threadIdx.x;
    __shared__ float w[NH_][L_];
    __shared__ int idxs[L_];
    __shared__ int s_len;
    if (tid == 0) {
        int m = masks[r];
        int st = span_ids[2 * r], en = span_ids[2 * r + 1];
        int len = m ? (en - st) : 0;
        len = len < 0 ? 0 : (len > L_ ? L_ : len);
        s_len = len;
    }
    __syncthreads();
    int len = s_len;
    if (len == 0) {
        for (int h2 = tid; h2 < H_ / 2; h2 += 256) ((unsigned*)out)[h2] = 0u;
        return;
    }
    if (tid < L_) {
        int p = span_ids[2 * r] + tid;
        idxs[tid] = p < 0 ? 0 : (p > T_ - 1 ? T_ - 1 : p);
    }
    __syncthreads();
    for (int i = tid; i < NH_ * L_; i += 256) {
        int n = i / L_, l = i % L_;
        w[n][l] = (l < len) ? stok[(size_t)(b * T_ + idxs[l]) * NH_ + n] * 0.125f : -INFINITY;
    }
    __syncthreads();
    if (tid < NH_) {
        float mx = -INFINITY;
        for (int l = 0; l < len; ++l) mx = fmaxf(mx, w[tid][l]);
        float sum = 0.f;
        for (int l = 0; l < len; ++l) { float e = __expf(w[tid][l] - mx); w[tid][l] = e; sum += e; }
        float inv = 1.f / sum;
        for (int l = 0; l < len; ++l) w[tid][l] *= inv;
    }
    __syncthreads();
    if (tid < 192) {
        int h0 = tid * 4, n = h0 >> 6;
        float a0 = 0.f, a1 = 0.f, a2 = 0.f, a3 = 0.f;
        for (int l = 0; l < len; ++l) {
            float wl = w[n][l];
            const unsigned short* vr = vtok + (size_t)(b * T_ + idxs[l]) * H_ + h0;
            uint2 u = *(const uint2*)vr;
            a0 += wl * bf2f((unsigned short)(u.x & 0xffff));
            a1 += wl * bf2f((unsigned short)(u.x >> 16));
            a2 += wl * bf2f((unsigned short)(u.y & 0xffff));
            a3 += wl * bf2f((unsigned short)(u.y >> 16));
        }
        uint2 o;
        o.x = (unsigned)f2bf(a0) | ((unsigned)f2bf(a1) << 16);
        o.y = (unsigned)f2bf(a2) | ((unsigned)f2bf(a3) << 16);
        *(uint2*)(out + h0) = o;
    }
}

// ---------------------------------------------------------------------------
// LayerNorm: out = LN(inp + res)*g + b, optional mask-zero, optional bf16 copy.
__global__ void k_ln(const float* __restrict__ inp, const float* __restrict__ res,
                     const float* __restrict__ g, const float* __restrict__ bt,
                     float* __restrict__ outp, unsigned short* __restrict__ outbf,
                     const int* __restrict__ masks, int res_broadcast, int apply_mask) {
    int r = blockIdx.x;
    const float* irow = inp + (size_t)r * H_;
    const float* rrow = res_broadcast ? res : res + (size_t)r * H_;
    float* orow = outp + (size_t)r * H_;
    int tid = threadIdx.x;
    float v[3];
    float lsum = 0.f;
#pragma unroll
    for (int i = 0; i < 3; ++i) {
        int h = tid + 256 * i;
        v[i] = irow[h] + rrow[h];
        lsum += v[i];
    }
    __shared__ float sh[256];
    sh[tid] = lsum;
    __syncthreads();
    for (int st = 128; st > 0; st >>= 1) {
        if (tid < st) sh[tid] += sh[tid + st];
        __syncthreads();
    }
    float mean = sh[0] * (1.f / H_);
    __syncthreads();
    float lvar = 0.f;
#pragma unroll
    for (int i = 0; i < 3; ++i) { float d = v[i] - mean; lvar += d * d; }
    sh[tid] = lvar;
    __syncthreads();
    for (int st = 128; st > 0; st >>= 1) {
        if (tid < st) sh[tid] += sh[tid + st];
        __syncthreads();
    }
    float var = sh[0] * (1.f / H_);
    float scale = rsqrtf(var + 1e-5f);
    float mfac = apply_mask ? (masks[r] ? 1.f : 0.f) : 1.f;
#pragma unroll
    for (int i = 0; i < 3; ++i) {
        int h = tid + 256 * i;
        float o = ((v[i] - mean) * scale * g[h] + bt[h]) * mfac;
        orow[h] = o;
        if (outbf) outbf[(size_t)r * H_ + h] = f2bf(o);
    }
}

// ---------------------------------------------------------------------------
extern "C" void kernel_launch(void* const* d_in, const int* in_sizes, int n_in,
                              void* d_out, int out_size, void* d_ws, size_t ws_size,
                              hipStream_t stream) {
    const float* token_reps = (const float*)d_in[0];
    const int*   span_ids   = (const int*)d_in[1];
    const int*   masks_raw  = (const int*)d_in[2];
    const float* pe   = (const float*)d_in[4];
    const float* dq   = (const float*)d_in[5];
    const float* in_w = (const float*)d_in[6];
    const float* in_b = (const float*)d_in[7];
    const float* ow   = (const float*)d_in[8];
    const float* ob   = (const float*)d_in[9];
    const float* g    = (const float*)d_in[10];
    const float* bt   = (const float*)d_in[11];
    const float* w1   = (const float*)d_in[12];
    const float* b1   = (const float*)d_in[13];
    const float* w2   = (const float*)d_in[14];
    const float* b2   = (const float*)d_in[15];

    const int BS = B_ * S_;        // 4096
    const int BT = B_ * T_;        // 1024

    // Workspace layout
    float* fws   = (float*)d_ws;
    float* stok  = fws;                         // 12288
    float* qv    = stok + BT * NH_;             // 768
    float* wqeff = qv + H_;                     // 9216
    float* A1    = wqeff + NH_ * H_;            // 3145728 (reused as f2)
    float* x1f   = A1 + (size_t)BS * H_;        // 3145728
    float* vtokf = x1f + (size_t)BS * H_;       // 786432 (fp32 split-K target)
    unsigned short* us   = (unsigned short*)(vtokf + (size_t)BT * H_);
    unsigned short* xbf  = us;                       // 786432
    unsigned short* vtok = xbf + (size_t)BT * H_;    // 786432
    unsigned short* ctx  = vtok + (size_t)BT * H_;   // 3145728
    unsigned short* x1bf = ctx + (size_t)BS * H_;    // 3145728
    unsigned short* f1   = x1bf + (size_t)BS * H_;   // 12582912
    unsigned short* wvb  = f1 + (size_t)BS * IM_;    // 589824
    unsigned short* owb  = wvb + H_ * H_;            // 589824
    unsigned short* w1b  = owb + H_ * H_;            // 2359296
    unsigned short* w2b  = w1b + IM_ * H_;           // 2359296
    int* maskn = (int*)(w2b + H_ * IM_);             // 4096
    float* f2 = A1;

    // 0. small prep + zero the split-K atomic targets
    hipMemsetAsync(vtokf, 0, (size_t)BT * H_ * 4, stream);
    hipMemsetAsync(A1, 0, (size_t)BS * H_ * 4, stream);
    k_mask<<<1, 1024, 0, stream>>>(masks_raw, maskn);
    k_q<<<H_ / 4, 256, 0, stream>>>(dq, in_w, in_b, qv);
    k_wqeff<<<(NH_ * H_ + 255) / 256, 256, 0, stream>>>(qv, in_w, wqeff);
    // 1. weight casts (fused single launch)
    {
        long total8 = ((long)2 * H_ * H_ + (long)2 * IM_ * H_) / 8;
        k_castw<<<(int)(total8 / 256), 256, 0, stream>>>(
            in_w + (size_t)2 * H_ * H_, ow, w1, w2, wvb, owb, w1b, w2b);
    }
    // 2. x = bf16(token_reps + pe)
    k_addpe<<<(BT * H_ / 8 + 255) / 256, 256, 0, stream>>>(token_reps, pe, xbf);
    // 3. per-token per-head scores
    k_stok<<<BT, 256, 0, stream>>>(xbf, wqeff, stok);
    // 4. vtokf (+)= x @ Wv^T + bv  (split-K x4, fp32 atomic), then cast bf16
    {
        dim3 grid(H_ / 128, BT / 128, 4);
        gemm_bt<false, false, true><<<grid, 256, 0, stream>>>(
            xbf, wvb, in_b + 2 * H_, vtokf, BT, H_, H_, H_ / 4);
        k_castv<<<(BT * H_ / 8 + 255) / 256, 256, 0, stream>>>(vtokf, vtok, BT * H_);
    }
    // 5. attention pooling -> ctx (bf16)
    k_attn<<<BS, 256, 0, stream>>>(stok, vtok, span_ids, maskn, ctx);
    // 6. A1 (+)= ctx @ ow^T + ob (split-K x4, fp32 atomic)
    {
        dim3 grid(H_ / 128, BS / 128, 4);
        gemm_bt<false, false, true><<<grid, 256, 0, stream>>>(
            ctx, owb, ob, A1, BS, H_, H_, H_ / 4);
    }
    // 7. x1 = LN(A1 + dq) -> fp32 + bf16
    k_ln<<<BS, 256, 0, stream>>>(A1, dq, g, bt, x1f, x1bf, nullptr, 1, 0);
    // 8. zero f2 (aliases A1, safe: LN already consumed it), FFN1
    hipMemsetAsync(f2, 0, (size_t)BS * H_ * 4, stream);
    {
        dim3 grid(IM_ / 128, BS / 128, 1);
        gemm_bt<true, true, false><<<grid, 256, 0, stream>>>(
            x1bf, w1b, b1, f1, BS, IM_, H_, H_);
    }
    // 9. f2 (+)= f1 @ w2^T + b2 (split-K x4, fp32 atomic)
    {
        dim3 grid(H_ / 128, BS / 128, 4);
        gemm_bt<false, false, true><<<grid, 256, 0, stream>>>(
            f1, w2b, b2, f2, BS, H_, IM_, IM_ / 4);
    }
    // 10. out = LN(f2 + x1) * mask
    k_ln<<<BS, 256, 0, stream>>>(f2, x1f, g, bt, (float*)d_out, nullptr, maskn, 0, 1);
}

// Round 8
// 254.211 us; speedup vs baseline: 1.2892x; 1.2892x over previous
//
#include <hip/hip_runtime.h>
#include <math.h>

// Problem constants
static constexpr int B_  = 2;
static constexpr int T_  = 512;
static constexpr int S_  = 2048;
static constexpr int H_  = 768;
static constexpr int L_  = 32;
static constexpr int NH_ = 12;
static constexpr int HD_ = 64;   // H/NH
static constexpr int IM_ = 3072; // 4*H

typedef __bf16 bf16x8 __attribute__((ext_vector_type(8)));
typedef float  f32x4  __attribute__((ext_vector_type(4)));

__device__ __forceinline__ float bf2f(unsigned short u) {
    return __uint_as_float(((unsigned)u) << 16);
}
__device__ __forceinline__ unsigned short f2bf(float f) {
    unsigned u = __float_as_uint(f);
    u += 0x7fffu + ((u >> 16) & 1u);   // RNE
    return (unsigned short)(u >> 16);
}
__device__ __forceinline__ void gl_lds16(const void* g, void* l) {
    __builtin_amdgcn_global_load_lds((const __attribute__((address_space(1))) void*)g,
                                     (__attribute__((address_space(3))) void*)l, 16, 0, 0);
}

// ---------------------------------------------------------------------------
// Mask normalization (int32 vs packed-byte autodetect)
__global__ void k_mask(const int* __restrict__ raw, int* __restrict__ mout) {
    __shared__ int bad;
    if (threadIdx.x == 0) bad = 0;
    __syncthreads();
    int v = raw[threadIdx.x];
    if (v != 0 && v != 1) bad = 1;
    __syncthreads();
    int byte_layout = bad;
    const unsigned char* rb = (const unsigned char*)raw;
    for (int i = threadIdx.x; i < B_ * S_; i += 1024)
        mout[i] = byte_layout ? (int)rb[i] : raw[i];
}

// q[i] = dq . Wq[i,:] + bq[i]  — one wave per output row (coalesced over h)
__global__ void k_q(const float* __restrict__ dq, const float* __restrict__ w,
                    const float* __restrict__ b, float* __restrict__ q) {
    int wv = threadIdx.x >> 6, lane = threadIdx.x & 63;
    int i = blockIdx.x * 4 + wv;
    const float* row = w + (size_t)i * H_;
    float acc = 0.f;
#pragma unroll
    for (int k = 0; k < 12; ++k) acc += dq[lane + 64 * k] * row[lane + 64 * k];
    for (int m = 32; m; m >>= 1) acc += __shfl_xor(acc, m, 64);
    if (lane == 0) q[i] = acc + b[i];
}

// Wq_eff[n,hh] = sum_d q[n*64+d] * Wk[n*64+d, hh]
__global__ void k_wqeff(const float* __restrict__ q, const float* __restrict__ w,
                        float* __restrict__ wq) {
    int i = blockIdx.x * 256 + threadIdx.x;
    if (i >= NH_ * H_) return;
    int n = i / H_, hh = i % H_;
    float acc = 0.f;
    for (int d = 0; d < HD_; ++d)
        acc += q[n * HD_ + d] * w[(size_t)(H_ + n * HD_ + d) * H_ + hh];
    wq[i] = acc;
}

// Fused weight cast: all four weight matrices fp32->bf16, 8 elems/thread.
__global__ void k_castw(const float* __restrict__ s0, const float* __restrict__ s1,
                        const float* __restrict__ s2, const float* __restrict__ s3,
                        unsigned short* __restrict__ d0, unsigned short* __restrict__ d1,
                        unsigned short* __restrict__ d2, unsigned short* __restrict__ d3) {
    const long n0 = (long)H_ * H_, n2 = (long)IM_ * H_;
    long gid = (long)(blockIdx.x * 256 + threadIdx.x) * 8;
    const float* s; unsigned short* d; long off;
    if (gid < n0)                { s = s0; d = d0; off = gid; }
    else if (gid < 2 * n0)       { s = s1; d = d1; off = gid - n0; }
    else if (gid < 2 * n0 + n2)  { s = s2; d = d2; off = gid - 2 * n0; }
    else                         { s = s3; d = d3; off = gid - 2 * n0 - n2; }
    float4 f0 = *(const float4*)(s + off);
    float4 f1 = *(const float4*)(s + off + 4);
    uint4 o;
    o.x = (unsigned)f2bf(f0.x) | ((unsigned)f2bf(f0.y) << 16);
    o.y = (unsigned)f2bf(f0.z) | ((unsigned)f2bf(f0.w) << 16);
    o.z = (unsigned)f2bf(f1.x) | ((unsigned)f2bf(f1.y) << 16);
    o.w = (unsigned)f2bf(f1.z) | ((unsigned)f2bf(f1.w) << 16);
    *(uint4*)(d + off) = o;
}

// sum of 2 fp32 partials -> bf16, 8 elems/thread
__global__ void k_castv2(const float* __restrict__ p0, const float* __restrict__ p1,
                         unsigned short* __restrict__ dst, int n) {
    int i = (blockIdx.x * 256 + threadIdx.x) * 8;
    if (i >= n) return;
    float4 a0 = *(const float4*)(p0 + i);
    float4 a1 = *(const float4*)(p0 + i + 4);
    float4 b0 = *(const float4*)(p1 + i);
    float4 b1 = *(const float4*)(p1 + i + 4);
    uint4 o;
    o.x = (unsigned)f2bf(a0.x + b0.x) | ((unsigned)f2bf(a0.y + b0.y) << 16);
    o.y = (unsigned)f2bf(a0.z + b0.z) | ((unsigned)f2bf(a0.w + b0.w) << 16);
    o.z = (unsigned)f2bf(a1.x + b1.x) | ((unsigned)f2bf(a1.y + b1.y) << 16);
    o.w = (unsigned)f2bf(a1.z + b1.z) | ((unsigned)f2bf(a1.w + b1.w) << 16);
    *(uint4*)(dst + i) = o;
}

// x_bf = bf16(token_reps + pe), 8 elems/thread
__global__ void k_addpe(const float* __restrict__ tr, const float* __restrict__ pe,
                        unsigned short* __restrict__ x) {
    int i = (blockIdx.x * 256 + threadIdx.x) * 8;
    if (i >= B_ * T_ * H_) return;
    float4 a0 = *(const float4*)(tr + i);
    float4 a1 = *(const float4*)(tr + i + 4);
    const float* pp = pe + (i % (T_ * H_));
    float4 p0 = *(const float4*)pp;
    float4 p1 = *(const float4*)(pp + 4);
    uint4 o;
    o.x = (unsigned)f2bf(a0.x + p0.x) | ((unsigned)f2bf(a0.y + p0.y) << 16);
    o.y = (unsigned)f2bf(a0.z + p0.z) | ((unsigned)f2bf(a0.w + p0.w) << 16);
    o.z = (unsigned)f2bf(a1.x + p1.x) | ((unsigned)f2bf(a1.y + p1.y) << 16);
    o.w = (unsigned)f2bf(a1.z + p1.z) | ((unsigned)f2bf(a1.w + p1.w) << 16);
    *(uint4*)(x + i) = o;
}

// stok[bt,n] = x_bf[bt,:] . wqeff[n,:]
__global__ void k_stok(const unsigned short* __restrict__ x, const float* __restrict__ wq,
                       float* __restrict__ stok) {
    int bt = blockIdx.x;
    int lane = threadIdx.x & 63, w = threadIdx.x >> 6;
    const unsigned short* xr = x + (size_t)bt * H_;
    float xv[12];
#pragma unroll
    for (int k = 0; k < 12; ++k) xv[k] = bf2f(xr[lane + 64 * k]);
#pragma unroll
    for (int hh = 0; hh < 3; ++hh) {
        int n = w * 3 + hh;
        const float* wr = wq + (size_t)n * H_;
        float acc = 0.f;
#pragma unroll
        for (int k = 0; k < 12; ++k) acc += xv[k] * wr[lane + 64 * k];
        for (int m = 32; m; m >>= 1) acc += __shfl_xor(acc, m, 64);
        if (lane == 0) stok[bt * NH_ + n] = acc;
    }
}

// ---------------------------------------------------------------------------
// bf16 MFMA GEMM, single 32KB LDS buffer + buffer-split-K (NO atomics).
// SPLIT: chunk z covers K-range [z*kLen, (z+1)*kLen), writes fp32 partial to
// Cout + z*M*N (plain stores); bias added by chunk 0 only; consumer sums.
// 128x128 tile, BK=64, 256 thr = 4 waves, wave 64x64 = 4x4 MFMA 16x16x32.
// XOR bank swizzle (16B chunk ^= row&7): verified 0 LDS conflicts (R6).
// 32 KB LDS => >=3 blocks/CU possible: sibling blocks hide the barrier
// drain (m114; R7 measured ~1000 cyc/iter at 3 blocks/CU vs 2700 at 1).
template <bool RELU, bool OBF, bool SPLIT>
__global__ __launch_bounds__(256)
void gemm_bt(const unsigned short* __restrict__ A, const unsigned short* __restrict__ W,
             const float* __restrict__ bias, void* __restrict__ Cout,
             int M, int N, int K, int kLen) {
    __shared__ unsigned short As[8192];    // 128 rows x 64 cols bf16
    __shared__ unsigned short Bs[8192];
    const int bm = blockIdx.y * 128, bn = blockIdx.x * 128;
    const int kOff = blockIdx.z * kLen;
    const int tid = threadIdx.x, lane = tid & 63, wid = tid >> 6;   // 0..3
    const int wm = (wid >> 1) * 64, wn = (wid & 1) * 64;
    const int r8 = lane >> 3, c8 = lane & 7;
    const int swc = (c8 ^ r8) * 8;                     // swizzled chunk offset
    const unsigned short* agp = A + (size_t)(bm + wid * 32 + r8) * K + kOff + swc;
    const unsigned short* bgp = W + (size_t)(bn + wid * 32 + r8) * K + kOff + swc;
    unsigned short* lA = As + wid * 2048;              // wave-uniform bases
    unsigned short* lB = Bs + wid * 2048;

    f32x4 acc[4][4];
#pragma unroll
    for (int i = 0; i < 4; ++i)
#pragma unroll
        for (int j = 0; j < 4; ++j) acc[i][j] = f32x4{0.f, 0.f, 0.f, 0.f};

    const int mrow = lane & 15;
    const int l7 = lane & 7;
    const int cq0 = lane >> 4;             // 16B chunk within 32-k window
    const int NIT = kLen >> 6;

    for (int it = 0; it < NIT; ++it) {
        const int k0 = it << 6;
#pragma unroll
        for (int j = 0; j < 4; ++j) {
            gl_lds16(agp + (size_t)(8 * j) * K + k0, lA + j * 512);
            gl_lds16(bgp + (size_t)(8 * j) * K + k0, lB + j * 512);
        }
        __syncthreads();                   // drains vmcnt: tile staged
        bf16x8 af[2][4], bfr[2][4];
#pragma unroll
        for (int s = 0; s < 2; ++s) {
            const int cq = s * 4 + cq0;
            const int sw = (cq ^ l7) * 8;
#pragma unroll
            for (int i = 0; i < 4; ++i)
                af[s][i] = *(const bf16x8*)(As + (wm + i * 16 + mrow) * 64 + sw);
#pragma unroll
            for (int j = 0; j < 4; ++j)
                bfr[s][j] = *(const bf16x8*)(Bs + (wn + j * 16 + mrow) * 64 + sw);
        }
#pragma unroll
        for (int s = 0; s < 2; ++s)
#pragma unroll
            for (int i = 0; i < 4; ++i)
#pragma unroll
                for (int j = 0; j < 4; ++j)
                    acc[i][j] = __builtin_amdgcn_mfma_f32_16x16x32_bf16(af[s][i], bfr[s][j], acc[i][j], 0, 0, 0);
        __syncthreads();                   // all waves done reading
    }

    // epilogue: C/D layout col=lane&15, row=(lane>>4)*4+reg (verified m89/m91)
    const bool addb = !SPLIT || blockIdx.z == 0;
    float* outp = SPLIT ? ((float*)Cout) + (size_t)blockIdx.z * M * N : (float*)Cout;
    const int lr = (lane >> 4) * 4, lc = lane & 15;
#pragma unroll
    for (int j = 0; j < 4; ++j) {
        int col = bn + wn + j * 16 + lc;
        float bv = addb ? bias[col] : 0.f;
#pragma unroll
        for (int i = 0; i < 4; ++i) {
            int row0 = bm + wm + i * 16 + lr;
#pragma unroll
            for (int r = 0; r < 4; ++r) {
                float v = acc[i][j][r] + bv;
                if (RELU) v = fmaxf(v, 0.f);
                if (OBF)
                    ((unsigned short*)Cout)[(size_t)(row0 + r) * N + col] = f2bf(v);
                else
                    outp[(size_t)(row0 + r) * N + col] = v;
            }
        }
    }
}

// ---------------------------------------------------------------------------
// Per-span attention pooling
__global__ void k_attn(const float* __restrict__ stok, const unsigned short* __restrict__ vtok,
                       const int* __restrict__ span_ids, const int* __restrict__ masks,
                       unsigned short* __restrict__ ctx) {
    int r = blockIdx.x, b = r / S_;
    unsigned short* out = ctx + (size_t)r * H_;
    int tid = threadIdx.x;
    __shared__ float w[NH_][L_];
    __shared__ int idxs[L_];
    __shared__ int s_len;
    if (tid == 0) {
        int m = masks[r];
        int st = span_ids[2 * r], en = span_ids[2 * r + 1];
        int len = m ? (en - st) : 0;
        len = len < 0 ? 0 : (len > L_ ? L_ : len);
        s_len = len;
    }
    __syncthreads();
    int len = s_len;
    if (len == 0) {
        for (int h2 = tid; h2 < H_ / 2; h2 += 256) ((unsigned*)out)[h2] = 0u;
        return;
    }
    if (tid < L_) {
        int p = span_ids[2 * r] + tid;
        idxs[tid] = p < 0 ? 0 : (p > T_ - 1 ? T_ - 1 : p);
    }
    __syncthreads();
    for (int i = tid; i < NH_ * L_; i += 256) {
        int n = i / L_, l = i % L_;
        w[n][l] = (l < len) ? stok[(size_t)(b * T_ + idxs[l]) * NH_ + n] * 0.125f : -INFINITY;
    }
    __syncthreads();
    if (tid < NH_) {
        float mx = -INFINITY;
        for (int l = 0; l < len; ++l) mx = fmaxf(mx, w[tid][l]);
        float sum = 0.f;
        for (int l = 0; l < len; ++l) { float e = __expf(w[tid][l] - mx); w[tid][l] = e; sum += e; }
        float inv = 1.f / sum;
        for (int l = 0; l < len; ++l) w[tid][l] *= inv;
    }
    __syncthreads();
    if (tid < 192) {
        int h0 = tid * 4, n = h0 >> 6;
        float a0 = 0.f, a1 = 0.f, a2 = 0.f, a3 = 0.f;
        for (int l = 0; l < len; ++l) {
            float wl = w[n][l];
            const unsigned short* vr = vtok + (size_t)(b * T_ + idxs[l]) * H_ + h0;
            uint2 u = *(const uint2*)vr;
            a0 += wl * bf2f((unsigned short)(u.x & 0xffff));
            a1 += wl * bf2f((unsigned short)(u.x >> 16));
            a2 += wl * bf2f((unsigned short)(u.y & 0xffff));
            a3 += wl * bf2f((unsigned short)(u.y >> 16));
        }
        uint2 o;
        o.x = (unsigned)f2bf(a0) | ((unsigned)f2bf(a1) << 16);
        o.y = (unsigned)f2bf(a2) | ((unsigned)f2bf(a3) << 16);
        *(uint2*)(out + h0) = o;
    }
}

// ---------------------------------------------------------------------------
// LayerNorm over (p0 + p1 + res): RESROW ? res = bf16 per-row : fp32 broadcast.
// MASKOUT ? fp32 masked output : bf16 output.
template <bool RESROW, bool MASKOUT>
__global__ void k_ln(const float* __restrict__ parts, size_t pstr,
                     const float* __restrict__ resf, const unsigned short* __restrict__ resb,
                     const float* __restrict__ g, const float* __restrict__ bt,
                     float* __restrict__ outf, unsigned short* __restrict__ outb,
                     const int* __restrict__ masks) {
    int r = blockIdx.x;
    const float* p0 = parts + (size_t)r * H_;
    const float* p1 = parts + pstr + (size_t)r * H_;
    int tid = threadIdx.x;
    float v[3];
    float lsum = 0.f;
#pragma unroll
    for (int i = 0; i < 3; ++i) {
        int h = tid + 256 * i;
        float res = RESROW ? bf2f(resb[(size_t)r * H_ + h]) : resf[h];
        v[i] = p0[h] + p1[h] + res;
        lsum += v[i];
    }
    __shared__ float sh[256];
    sh[tid] = lsum;
    __syncthreads();
    for (int st = 128; st > 0; st >>= 1) {
        if (tid < st) sh[tid] += sh[tid + st];
        __syncthreads();
    }
    float mean = sh[0] * (1.f / H_);
    __syncthreads();
    float lvar = 0.f;
#pragma unroll
    for (int i = 0; i < 3; ++i) { float d = v[i] - mean; lvar += d * d; }
    sh[tid] = lvar;
    __syncthreads();
    for (int st = 128; st > 0; st >>= 1) {
        if (tid < st) sh[tid] += sh[tid + st];
        __syncthreads();
    }
    float var = sh[0] * (1.f / H_);
    float scale = rsqrtf(var + 1e-5f);
    float mfac = 1.f;
    if (MASKOUT) mfac = masks[r] ? 1.f : 0.f;
#pragma unroll
    for (int i = 0; i < 3; ++i) {
        int h = tid + 256 * i;
        float o = ((v[i] - mean) * scale * g[h] + bt[h]) * mfac;
        if (MASKOUT) outf[(size_t)r * H_ + h] = o;
        else         outb[(size_t)r * H_ + h] = f2bf(o);
    }
}

// ---------------------------------------------------------------------------
extern "C" void kernel_launch(void* const* d_in, const int* in_sizes, int n_in,
                              void* d_out, int out_size, void* d_ws, size_t ws_size,
                              hipStream_t stream) {
    const float* token_reps = (const float*)d_in[0];
    const int*   span_ids   = (const int*)d_in[1];
    const int*   masks_raw  = (const int*)d_in[2];
    const float* pe   = (const float*)d_in[4];
    const float* dq   = (const float*)d_in[5];
    const float* in_w = (const float*)d_in[6];
    const float* in_b = (const float*)d_in[7];
    const float* ow   = (const float*)d_in[8];
    const float* ob   = (const float*)d_in[9];
    const float* g    = (const float*)d_in[10];
    const float* bt   = (const float*)d_in[11];
    const float* w1   = (const float*)d_in[12];
    const float* b1   = (const float*)d_in[13];
    const float* w2   = (const float*)d_in[14];
    const float* b2   = (const float*)d_in[15];

    const int BS = B_ * S_;        // 4096
    const int BT = B_ * T_;        // 1024

    // Workspace layout (floats first, then bf16, then ints)
    float* fws   = (float*)d_ws;
    float* stok  = fws;                         // 12288
    float* qv    = stok + BT * NH_;             // 768
    float* wqeff = qv + H_;                     // 9216
    float* big   = wqeff + NH_ * H_;            // 2 * BS*H = 6291456 fl (25.2MB)
    // big lifetimes (non-overlapping): vt2 (step4->4b), op2 (6->7), f2p (9->10)
    unsigned short* us   = (unsigned short*)(big + (size_t)2 * BS * H_);
    unsigned short* xbf  = us;                       // 786432
    unsigned short* vtok = xbf + (size_t)BT * H_;    // 786432
    unsigned short* ctx  = vtok + (size_t)BT * H_;   // 3145728
    unsigned short* x1bf = ctx + (size_t)BS * H_;    // 3145728
    unsigned short* f1   = x1bf + (size_t)BS * H_;   // 12582912
    unsigned short* wvb  = f1 + (size_t)BS * IM_;    // 589824
    unsigned short* owb  = wvb + H_ * H_;            // 589824
    unsigned short* w1b  = owb + H_ * H_;            // 2359296
    unsigned short* w2b  = w1b + IM_ * H_;           // 2359296
    int* maskn = (int*)(w2b + H_ * IM_);             // 4096

    // 0. small prep
    k_mask<<<1, 1024, 0, stream>>>(masks_raw, maskn);
    k_q<<<H_ / 4, 256, 0, stream>>>(dq, in_w, in_b, qv);
    k_wqeff<<<(NH_ * H_ + 255) / 256, 256, 0, stream>>>(qv, in_w, wqeff);
    // 1. weight casts (fused single launch)
    {
        long total8 = ((long)2 * H_ * H_ + (long)2 * IM_ * H_) / 8;
        k_castw<<<(int)(total8 / 256), 256, 0, stream>>>(
            in_w + (size_t)2 * H_ * H_, ow, w1, w2, wvb, owb, w1b, w2b);
    }
    // 2. x = bf16(token_reps + pe)
    k_addpe<<<(BT * H_ / 8 + 255) / 256, 256, 0, stream>>>(token_reps, pe, xbf);
    // 3. per-token per-head scores
    k_stok<<<BT, 256, 0, stream>>>(xbf, wqeff, stok);
    // 4. vt2[z] = x @ Wv[zK]^T (+bv on z=0), split-K x2 -> sum-cast to bf16
    {
        dim3 grid(H_ / 128, BT / 128, 2);
        gemm_bt<false, false, true><<<grid, 256, 0, stream>>>(
            xbf, wvb, in_b + 2 * H_, big, BT, H_, H_, H_ / 2);
        k_castv2<<<(BT * H_ / 8 + 255) / 256, 256, 0, stream>>>(
            big, big + (size_t)BT * H_, vtok, BT * H_);
    }
    // 5. attention pooling -> ctx (bf16)
    k_attn<<<BS, 256, 0, stream>>>(stok, vtok, span_ids, maskn, ctx);
    // 6. op2[z] = ctx @ ow[zK]^T (+ob on z=0), split-K x2
    {
        dim3 grid(H_ / 128, BS / 128, 2);
        gemm_bt<false, false, true><<<grid, 256, 0, stream>>>(
            ctx, owb, ob, big, BS, H_, H_, H_ / 2);
    }
    // 7. x1bf = bf16(LN(op2[0]+op2[1] + dq))
    k_ln<false, false><<<BS, 256, 0, stream>>>(
        big, (size_t)BS * H_, dq, nullptr, g, bt, nullptr, x1bf, nullptr);
    // 8. f1 = bf16(relu(x1 @ w1^T + b1))  (768 blocks, no split)
    {
        dim3 grid(IM_ / 128, BS / 128, 1);
        gemm_bt<true, true, false><<<grid, 256, 0, stream>>>(
            x1bf, w1b, b1, f1, BS, IM_, H_, H_);
    }
    // 9. f2p[z] = f1 @ w2[zK]^T (+b2 on z=0), split-K x2
    {
        dim3 grid(H_ / 128, BS / 128, 2);
        gemm_bt<false, false, true><<<grid, 256, 0, stream>>>(
            f1, w2b, b2, big, BS, H_, IM_, IM_ / 2);
    }
    // 10. out = LN(f2p[0]+f2p[1] + x1) * mask
    k_ln<true, true><<<BS, 256, 0, stream>>>(
        big, (size_t)BS * H_, nullptr, x1bf, g, bt, (float*)d_out, nullptr, maskn);
}

// Round 9
// 244.565 us; speedup vs baseline: 1.3401x; 1.0394x over previous
//
#include <hip/hip_runtime.h>
#include <math.h>

// Problem constants
static constexpr int B_  = 2;
static constexpr int T_  = 512;
static constexpr int S_  = 2048;
static constexpr int H_  = 768;
static constexpr int L_  = 32;
static constexpr int NH_ = 12;
static constexpr int HD_ = 64;   // H/NH
static constexpr int IM_ = 3072; // 4*H

typedef __bf16 bf16x8 __attribute__((ext_vector_type(8)));
typedef float  f32x4  __attribute__((ext_vector_type(4)));

__device__ __forceinline__ float bf2f(unsigned short u) {
    return __uint_as_float(((unsigned)u) << 16);
}
__device__ __forceinline__ unsigned short f2bf(float f) {
    unsigned u = __float_as_uint(f);
    u += 0x7fffu + ((u >> 16) & 1u);   // RNE
    return (unsigned short)(u >> 16);
}
__device__ __forceinline__ void gl_lds16(const void* g, void* l) {
    __builtin_amdgcn_global_load_lds((const __attribute__((address_space(1))) void*)g,
                                     (__attribute__((address_space(3))) void*)l, 16, 0, 0);
}

// ---------------------------------------------------------------------------
// Mask normalization (int32 vs packed-byte autodetect)
__global__ void k_mask(const int* __restrict__ raw, int* __restrict__ mout) {
    __shared__ int bad;
    if (threadIdx.x == 0) bad = 0;
    __syncthreads();
    int v = raw[threadIdx.x];
    if (v != 0 && v != 1) bad = 1;
    __syncthreads();
    int byte_layout = bad;
    const unsigned char* rb = (const unsigned char*)raw;
    for (int i = threadIdx.x; i < B_ * S_; i += 1024)
        mout[i] = byte_layout ? (int)rb[i] : raw[i];
}

// q[i] = dq . Wq[i,:] + bq[i]  — one wave per output row (coalesced over h)
__global__ void k_q(const float* __restrict__ dq, const float* __restrict__ w,
                    const float* __restrict__ b, float* __restrict__ q) {
    int wv = threadIdx.x >> 6, lane = threadIdx.x & 63;
    int i = blockIdx.x * 4 + wv;
    const float* row = w + (size_t)i * H_;
    float acc = 0.f;
#pragma unroll
    for (int k = 0; k < 12; ++k) acc += dq[lane + 64 * k] * row[lane + 64 * k];
    for (int m = 32; m; m >>= 1) acc += __shfl_xor(acc, m, 64);
    if (lane == 0) q[i] = acc + b[i];
}

// Wq_eff[n,hh] = sum_d q[n*64+d] * Wk[n*64+d, hh]
__global__ void k_wqeff(const float* __restrict__ q, const float* __restrict__ w,
                        float* __restrict__ wq) {
    int i = blockIdx.x * 256 + threadIdx.x;
    if (i >= NH_ * H_) return;
    int n = i / H_, hh = i % H_;
    float acc = 0.f;
    for (int d = 0; d < HD_; ++d)
        acc += q[n * HD_ + d] * w[(size_t)(H_ + n * HD_ + d) * H_ + hh];
    wq[i] = acc;
}

// Fused weight cast: all four weight matrices fp32->bf16, 8 elems/thread.
__global__ void k_castw(const float* __restrict__ s0, const float* __restrict__ s1,
                        const float* __restrict__ s2, const float* __restrict__ s3,
                        unsigned short* __restrict__ d0, unsigned short* __restrict__ d1,
                        unsigned short* __restrict__ d2, unsigned short* __restrict__ d3) {
    const long n0 = (long)H_ * H_, n2 = (long)IM_ * H_;
    long gid = (long)(blockIdx.x * 256 + threadIdx.x) * 8;
    const float* s; unsigned short* d; long off;
    if (gid < n0)                { s = s0; d = d0; off = gid; }
    else if (gid < 2 * n0)       { s = s1; d = d1; off = gid - n0; }
    else if (gid < 2 * n0 + n2)  { s = s2; d = d2; off = gid - 2 * n0; }
    else                         { s = s3; d = d3; off = gid - 2 * n0 - n2; }
    float4 f0 = *(const float4*)(s + off);
    float4 f1 = *(const float4*)(s + off + 4);
    uint4 o;
    o.x = (unsigned)f2bf(f0.x) | ((unsigned)f2bf(f0.y) << 16);
    o.y = (unsigned)f2bf(f0.z) | ((unsigned)f2bf(f0.w) << 16);
    o.z = (unsigned)f2bf(f1.x) | ((unsigned)f2bf(f1.y) << 16);
    o.w = (unsigned)f2bf(f1.z) | ((unsigned)f2bf(f1.w) << 16);
    *(uint4*)(d + off) = o;
}

// sum of 4 bf16 partial buffers -> bf16, 4 elems/thread
__global__ void k_castv4(const unsigned short* __restrict__ p, size_t pstr,
                         unsigned short* __restrict__ dst, int n) {
    int i = (blockIdx.x * 256 + threadIdx.x) * 4;
    if (i >= n) return;
    float a0 = 0.f, a1 = 0.f, a2 = 0.f, a3 = 0.f;
#pragma unroll
    for (int z = 0; z < 4; ++z) {
        uint2 u = *(const uint2*)(p + z * pstr + i);
        a0 += bf2f((unsigned short)(u.x & 0xffff));
        a1 += bf2f((unsigned short)(u.x >> 16));
        a2 += bf2f((unsigned short)(u.y & 0xffff));
        a3 += bf2f((unsigned short)(u.y >> 16));
    }
    uint2 o;
    o.x = (unsigned)f2bf(a0) | ((unsigned)f2bf(a1) << 16);
    o.y = (unsigned)f2bf(a2) | ((unsigned)f2bf(a3) << 16);
    *(uint2*)(dst + i) = o;
}

// x_bf = bf16(token_reps + pe), 8 elems/thread
__global__ void k_addpe(const float* __restrict__ tr, const float* __restrict__ pe,
                        unsigned short* __restrict__ x) {
    int i = (blockIdx.x * 256 + threadIdx.x) * 8;
    if (i >= B_ * T_ * H_) return;
    float4 a0 = *(const float4*)(tr + i);
    float4 a1 = *(const float4*)(tr + i + 4);
    const float* pp = pe + (i % (T_ * H_));
    float4 p0 = *(const float4*)pp;
    float4 p1 = *(const float4*)(pp + 4);
    uint4 o;
    o.x = (unsigned)f2bf(a0.x + p0.x) | ((unsigned)f2bf(a0.y + p0.y) << 16);
    o.y = (unsigned)f2bf(a0.z + p0.z) | ((unsigned)f2bf(a0.w + p0.w) << 16);
    o.z = (unsigned)f2bf(a1.x + p1.x) | ((unsigned)f2bf(a1.y + p1.y) << 16);
    o.w = (unsigned)f2bf(a1.z + p1.z) | ((unsigned)f2bf(a1.w + p1.w) << 16);
    *(uint4*)(x + i) = o;
}

// stok[bt,n] = x_bf[bt,:] . wqeff[n,:]
__global__ void k_stok(const unsigned short* __restrict__ x, const float* __restrict__ wq,
                       float* __restrict__ stok) {
    int bt = blockIdx.x;
    int lane = threadIdx.x & 63, w = threadIdx.x >> 6;
    const unsigned short* xr = x + (size_t)bt * H_;
    float xv[12];
#pragma unroll
    for (int k = 0; k < 12; ++k) xv[k] = bf2f(xr[lane + 64 * k]);
#pragma unroll
    for (int hh = 0; hh < 3; ++hh) {
        int n = w * 3 + hh;
        const float* wr = wq + (size_t)n * H_;
        float acc = 0.f;
#pragma unroll
        for (int k = 0; k < 12; ++k) acc += xv[k] * wr[lane + 64 * k];
        for (int m = 32; m; m >>= 1) acc += __shfl_xor(acc, m, 64);
        if (lane == 0) stok[bt * NH_ + n] = acc;
    }
}

// ---------------------------------------------------------------------------
// bf16 MFMA GEMM, single 32KB LDS buffer, buffer-split-K with bf16 partials,
// XCD-pinned 1D swizzle. Always writes bf16 (SPLIT: chunk z at Cout+z*M*N,
// bias on z=0; else direct output with optional ReLU).
// 128x128 tile, BK=64, 256 thr = 4 waves, wave 64x64 = 4x4 MFMA 16x16x32.
// XOR bank swizzle (16B chunk ^= row&7): 0 LDS conflicts (verified R6).
// Swizzle: q=bid%8 (XCD), all TX x-tiles of group g=(gi*8+q) run on XCD q =>
// A-tile rows are fetched by one XCD only (L2 locality). Requires TY*SP%8==0.
template <bool RELU, bool SPLIT>
__global__ __launch_bounds__(256)
void gemm_bt(const unsigned short* __restrict__ A, const unsigned short* __restrict__ W,
             const float* __restrict__ bias, unsigned short* __restrict__ Cout,
             int M, int N, int K, int kLen, int TX, int SP) {
    __shared__ unsigned short As[8192];    // 128 rows x 64 cols bf16
    __shared__ unsigned short Bs[8192];
    // --- XCD-pinned block swizzle ---
    const int qx = blockIdx.x & 7, t = blockIdx.x >> 3;
    const int gi = t / TX, x = t - gi * TX;
    const int g = gi * 8 + qx;
    int y, z;
    if (SPLIT) { y = g / SP; z = g - y * SP; } else { y = g; z = 0; }
    const int bm = y * 128, bn = x * 128;
    const int kOff = z * kLen;

    const int tid = threadIdx.x, lane = tid & 63, wid = tid >> 6;   // 0..3
    const int wm = (wid >> 1) * 64, wn = (wid & 1) * 64;
    const int r8 = lane >> 3, c8 = lane & 7;
    const int swc = (c8 ^ r8) * 8;                     // swizzled chunk offset
    const unsigned short* agp = A + (size_t)(bm + wid * 32 + r8) * K + kOff + swc;
    const unsigned short* bgp = W + (size_t)(bn + wid * 32 + r8) * K + kOff + swc;
    unsigned short* lA = As + wid * 2048;              // wave-uniform bases
    unsigned short* lB = Bs + wid * 2048;

    f32x4 acc[4][4];
#pragma unroll
    for (int i = 0; i < 4; ++i)
#pragma unroll
        for (int j = 0; j < 4; ++j) acc[i][j] = f32x4{0.f, 0.f, 0.f, 0.f};

    const int mrow = lane & 15;
    const int l7 = lane & 7;
    const int cq0 = lane >> 4;             // 16B chunk within 32-k window
    const int NIT = kLen >> 6;

    for (int it = 0; it < NIT; ++it) {
        const int k0 = it << 6;
#pragma unroll
        for (int j = 0; j < 4; ++j) {
            gl_lds16(agp + (size_t)(8 * j) * K + k0, lA + j * 512);
            gl_lds16(bgp + (size_t)(8 * j) * K + k0, lB + j * 512);
        }
        __syncthreads();                   // drains vmcnt: tile staged
        bf16x8 af[2][4], bfr[2][4];
#pragma unroll
        for (int s = 0; s < 2; ++s) {
            const int cq = s * 4 + cq0;
            const int sw = (cq ^ l7) * 8;
#pragma unroll
            for (int i = 0; i < 4; ++i)
                af[s][i] = *(const bf16x8*)(As + (wm + i * 16 + mrow) * 64 + sw);
#pragma unroll
            for (int j = 0; j < 4; ++j)
                bfr[s][j] = *(const bf16x8*)(Bs + (wn + j * 16 + mrow) * 64 + sw);
        }
#pragma unroll
        for (int s = 0; s < 2; ++s)
#pragma unroll
            for (int i = 0; i < 4; ++i)
#pragma unroll
                for (int j = 0; j < 4; ++j)
                    acc[i][j] = __builtin_amdgcn_mfma_f32_16x16x32_bf16(af[s][i], bfr[s][j], acc[i][j], 0, 0, 0);
        __syncthreads();                   // all waves done reading
    }

    // epilogue: C/D layout col=lane&15, row=(lane>>4)*4+reg (verified m89/m91)
    const bool addb = !SPLIT || z == 0;
    unsigned short* outp = SPLIT ? Cout + (size_t)z * M * N : Cout;
    const int lr = (lane >> 4) * 4, lc = lane & 15;
#pragma unroll
    for (int j = 0; j < 4; ++j) {
        int col = bn + wn + j * 16 + lc;
        float bv = addb ? bias[col] : 0.f;
#pragma unroll
        for (int i = 0; i < 4; ++i) {
            int row0 = bm + wm + i * 16 + lr;
#pragma unroll
            for (int r = 0; r < 4; ++r) {
                float v = acc[i][j][r] + bv;
                if (RELU) v = fmaxf(v, 0.f);
                outp[(size_t)(row0 + r) * N + col] = f2bf(v);
            }
        }
    }
}

// ---------------------------------------------------------------------------
// Per-span attention pooling
__global__ void k_attn(const float* __restrict__ stok, const unsigned short* __restrict__ vtok,
                       const int* __restrict__ span_ids, const int* __restrict__ masks,
                       unsigned short* __restrict__ ctx) {
    int r = blockIdx.x, b = r / S_;
    unsigned short* out = ctx + (size_t)r * H_;
    int tid = threadIdx.x;
    __shared__ float w[NH_][L_];
    __shared__ int idxs[L_];
    __shared__ int s_len;
    if (tid == 0) {
        int m = masks[r];
        int st = span_ids[2 * r], en = span_ids[2 * r + 1];
        int len = m ? (en - st) : 0;
        len = len < 0 ? 0 : (len > L_ ? L_ : len);
        s_len = len;
    }
    __syncthreads();
    int len = s_len;
    if (len == 0) {
        for (int h2 = tid; h2 < H_ / 2; h2 += 256) ((unsigned*)out)[h2] = 0u;
        return;
    }
    if (tid < L_) {
        int p = span_ids[2 * r] + tid;
        idxs[tid] = p < 0 ? 0 : (p > T_ - 1 ? T_ - 1 : p);
    }
    __syncthreads();
    for (int i = tid; i < NH_ * L_; i += 256) {
        int n = i / L_, l = i % L_;
        w[n][l] = (l < len) ? stok[(size_t)(b * T_ + idxs[l]) * NH_ + n] * 0.125f : -INFINITY;
    }
    __syncthreads();
    if (tid < NH_) {
        float mx = -INFINITY;
        for (int l = 0; l < len; ++l) mx = fmaxf(mx, w[tid][l]);
        float sum = 0.f;
        for (int l = 0; l < len; ++l) { float e = __expf(w[tid][l] - mx); w[tid][l] = e; sum += e; }
        float inv = 1.f / sum;
        for (int l = 0; l < len; ++l) w[tid][l] *= inv;
    }
    __syncthreads();
    if (tid < 192) {
        int h0 = tid * 4, n = h0 >> 6;
        float a0 = 0.f, a1 = 0.f, a2 = 0.f, a3 = 0.f;
        for (int l = 0; l < len; ++l) {
            float wl = w[n][l];
            const unsigned short* vr = vtok + (size_t)(b * T_ + idxs[l]) * H_ + h0;
            uint2 u = *(const uint2*)vr;
            a0 += wl * bf2f((unsigned short)(u.x & 0xffff));
            a1 += wl * bf2f((unsigned short)(u.x >> 16));
            a2 += wl * bf2f((unsigned short)(u.y & 0xffff));
            a3 += wl * bf2f((unsigned short)(u.y >> 16));
        }
        uint2 o;
        o.x = (unsigned)f2bf(a0) | ((unsigned)f2bf(a1) << 16);
        o.y = (unsigned)f2bf(a2) | ((unsigned)f2bf(a3) << 16);
        *(uint2*)(out + h0) = o;
    }
}

// ---------------------------------------------------------------------------
// LayerNorm over (sum of 4 bf16 partials + res).
// RESROW: res = bf16 per-row; else fp32 broadcast vector.
// MASKOUT: masked fp32 output; else bf16 output.
template <bool RESROW, bool MASKOUT>
__global__ void k_ln(const unsigned short* __restrict__ parts, size_t pstr,
                     const float* __restrict__ resf, const unsigned short* __restrict__ resb,
                     const float* __restrict__ g, const float* __restrict__ bt,
                     float* __restrict__ outf, unsigned short* __restrict__ outb,
                     const int* __restrict__ masks) {
    int r = blockIdx.x;
    int tid = threadIdx.x;
    float v[3];
    float lsum = 0.f;
#pragma unroll
    for (int i = 0; i < 3; ++i) {
        int h = tid + 256 * i;
        float s = RESROW ? bf2f(resb[(size_t)r * H_ + h]) : resf[h];
#pragma unroll
        for (int z = 0; z < 4; ++z)
            s += bf2f(parts[z * pstr + (size_t)r * H_ + h]);
        v[i] = s;
        lsum += s;
    }
    __shared__ float sh[256];
    sh[tid] = lsum;
    __syncthreads();
    for (int st = 128; st > 0; st >>= 1) {
        if (tid < st) sh[tid] += sh[tid + st];
        __syncthreads();
    }
    float mean = sh[0] * (1.f / H_);
    __syncthreads();
    float lvar = 0.f;
#pragma unroll
    for (int i = 0; i < 3; ++i) { float d = v[i] - mean; lvar += d * d; }
    sh[tid] = lvar;
    __syncthreads();
    for (int st = 128; st > 0; st >>= 1) {
        if (tid < st) sh[tid] += sh[tid + st];
        __syncthreads();
    }
    float var = sh[0] * (1.f / H_);
    float scale = rsqrtf(var + 1e-5f);
    float mfac = 1.f;
    if (MASKOUT) mfac = masks[r] ? 1.f : 0.f;
#pragma unroll
    for (int i = 0; i < 3; ++i) {
        int h = tid + 256 * i;
        float o = ((v[i] - mean) * scale * g[h] + bt[h]) * mfac;
        if (MASKOUT) outf[(size_t)r * H_ + h] = o;
        else         outb[(size_t)r * H_ + h] = f2bf(o);
    }
}

// ---------------------------------------------------------------------------
extern "C" void kernel_launch(void* const* d_in, const int* in_sizes, int n_in,
                              void* d_out, int out_size, void* d_ws, size_t ws_size,
                              hipStream_t stream) {
    const float* token_reps = (const float*)d_in[0];
    const int*   span_ids   = (const int*)d_in[1];
    const int*   masks_raw  = (const int*)d_in[2];
    const float* pe   = (const float*)d_in[4];
    const float* dq   = (const float*)d_in[5];
    const float* in_w = (const float*)d_in[6];
    const float* in_b = (const float*)d_in[7];
    const float* ow   = (const float*)d_in[8];
    const float* ob   = (const float*)d_in[9];
    const float* g    = (const float*)d_in[10];
    const float* bt   = (const float*)d_in[11];
    const float* w1   = (const float*)d_in[12];
    const float* b1   = (const float*)d_in[13];
    const float* w2   = (const float*)d_in[14];
    const float* b2   = (const float*)d_in[15];

    const int BS = B_ * S_;        // 4096
    const int BT = B_ * T_;        // 1024

    // Workspace layout
    float* fws   = (float*)d_ws;
    float* stok  = fws;                         // 12288
    float* qv    = stok + BT * NH_;             // 768
    float* wqeff = qv + H_;                     // 9216
    unsigned short* us = (unsigned short*)(wqeff + NH_ * H_);
    unsigned short* pbuf = us;                       // 4 * BS*H = 12.58M ushort
    unsigned short* xbf  = pbuf + (size_t)4 * BS * H_; // 786432
    unsigned short* vtok = xbf + (size_t)BT * H_;    // 786432
    unsigned short* ctx  = vtok + (size_t)BT * H_;   // 3145728
    unsigned short* x1bf = ctx + (size_t)BS * H_;    // 3145728
    unsigned short* f1   = x1bf + (size_t)BS * H_;   // 12582912
    unsigned short* wvb  = f1 + (size_t)BS * IM_;    // 589824
    unsigned short* owb  = wvb + H_ * H_;            // 589824
    unsigned short* w1b  = owb + H_ * H_;            // 2359296
    unsigned short* w2b  = w1b + IM_ * H_;           // 2359296
    int* maskn = (int*)(w2b + H_ * IM_);             // 4096

    // 0. small prep
    k_mask<<<1, 1024, 0, stream>>>(masks_raw, maskn);
    k_q<<<H_ / 4, 256, 0, stream>>>(dq, in_w, in_b, qv);
    k_wqeff<<<(NH_ * H_ + 255) / 256, 256, 0, stream>>>(qv, in_w, wqeff);
    // 1. weight casts (fused single launch)
    {
        long total8 = ((long)2 * H_ * H_ + (long)2 * IM_ * H_) / 8;
        k_castw<<<(int)(total8 / 256), 256, 0, stream>>>(
            in_w + (size_t)2 * H_ * H_, ow, w1, w2, wvb, owb, w1b, w2b);
    }
    // 2. x = bf16(token_reps + pe)
    k_addpe<<<(BT * H_ / 8 + 255) / 256, 256, 0, stream>>>(token_reps, pe, xbf);
    // 3. per-token per-head scores
    k_stok<<<BT, 256, 0, stream>>>(xbf, wqeff, stok);
    // 4. vtok partials (split-K x4, bf16) -> sum-cast
    {
        // TX=6 (N=768/128), TY=8 (M=1024/128), SP=4: blocks = TY*SP*TX = 192
        gemm_bt<false, true><<<192, 256, 0, stream>>>(
            xbf, wvb, in_b + 2 * H_, pbuf, BT, H_, H_, H_ / 4, 6, 4);
        k_castv4<<<(BT * H_ / 4 + 255) / 256, 256, 0, stream>>>(
            pbuf, (size_t)BT * H_, vtok, BT * H_);
    }
    // 5. attention pooling -> ctx (bf16)
    k_attn<<<BS, 256, 0, stream>>>(stok, vtok, span_ids, maskn, ctx);
    // 6. out_proj partials (split-K x4, bf16): TX=6, TY=32, SP=4 -> 768 blocks
    gemm_bt<false, true><<<768, 256, 0, stream>>>(
        ctx, owb, ob, pbuf, BS, H_, H_, H_ / 4, 6, 4);
    // 7. x1bf = bf16(LN(sum(partials) + dq))
    k_ln<false, false><<<BS, 256, 0, stream>>>(
        pbuf, (size_t)BS * H_, dq, nullptr, g, bt, nullptr, x1bf, nullptr);
    // 8. f1 = bf16(relu(x1 @ w1^T + b1)): TX=24, TY=32, SP=1 -> 768 blocks
    gemm_bt<true, false><<<768, 256, 0, stream>>>(
        x1bf, w1b, b1, f1, BS, IM_, H_, H_, 24, 1);
    // 9. FFN2 partials (split-K x4, bf16): TX=6, TY=32, SP=4 -> 768 blocks
    gemm_bt<false, true><<<768, 256, 0, stream>>>(
        f1, w2b, b2, pbuf, BS, H_, IM_, IM_ / 4, 6, 4);
    // 10. out = LN(sum(partials) + x1) * mask
    k_ln<true, true><<<BS, 256, 0, stream>>>(
        pbuf, (size_t)BS * H_, nullptr, x1bf, g, bt, (float*)d_out, nullptr, maskn);
}